// Round 1
// baseline (2731.502 us; speedup 1.0000x reference)
//
#include <hip/hip_runtime.h>
#include <stdint.h>

// LDS row stride: 68 floats (64 + 4 pad) breaks the power-of-2 bank pattern
// while keeping 16B alignment for float4 rows (68*4B = 272B, col0*4B = 16B-aligned).
#define LDS_S 68
#define MSZ (64 * LDS_S)

typedef float v4f __attribute__((ext_vector_type(4)));

// C = A @ B for 64x64 matrices in LDS (stride LDS_S). Each thread owns a 4x4
// output tile (thread grid 16x16). Ends with __syncthreads() so the next step
// may read C and overwrite whichever buffer just went dead.
__device__ __forceinline__ void mm64(const float* __restrict__ A,
                                     const float* __restrict__ B,
                                     float* __restrict__ C,
                                     int row0, int col0) {
  float acc[4][4];
#pragma unroll
  for (int r = 0; r < 4; ++r)
#pragma unroll
    for (int c = 0; c < 4; ++c) acc[r][c] = 0.0f;

#pragma unroll
  for (int kk = 0; kk < 64; kk += 4) {
    v4f av[4], bv[4];
#pragma unroll
    for (int r = 0; r < 4; ++r)
      av[r] = *(const v4f*)(A + (row0 + r) * LDS_S + kk);
#pragma unroll
    for (int k2 = 0; k2 < 4; ++k2)
      bv[k2] = *(const v4f*)(B + (kk + k2) * LDS_S + col0);
#pragma unroll
    for (int r = 0; r < 4; ++r)
#pragma unroll
      for (int k2 = 0; k2 < 4; ++k2)
#pragma unroll
        for (int c = 0; c < 4; ++c)
          acc[r][c] = fmaf(av[r][k2], bv[k2][c], acc[r][c]);
  }
#pragma unroll
  for (int r = 0; r < 4; ++r) {
    v4f v;
    v[0] = acc[r][0]; v[1] = acc[r][1]; v[2] = acc[r][2]; v[3] = acc[r][3];
    *(v4f*)(C + (row0 + r) * LDS_S + col0) = v;
  }
  __syncthreads();
}

// One block per batch element. x, scores, alpha live in registers; the matrix
// power chains run through 3 LDS buffers with a fixed (srcA,srcB,dst) schedule.
//
// p=63 schedule (result = m^63 ends in buffer 1), verified:
//   B1=B0*B0(m^2) B2=B0*B1(m^3) B0=B1*B1(m^4) B1=B2*B0(m^7) B2=B0*B0(m^8)
//   B0=B1*B2(m^15) B1=B2*B2(m^16) B2=B0*B1(m^31) B0=B1*B1(m^32) B1=B2*B0(m^63)
// p=30: only trace needed -> stop at rb=m^14 (B1), m4=m^16 (B0),
//   trace(m^30) = sum_{i,k} rb[i,k]*m4[k,i].
__global__ __launch_bounds__(256, 2) void dag_iter_kernel(
    const float* __restrict__ adj, float* __restrict__ out, int niter) {
  __shared__ float BUF[3 * MSZ];
  __shared__ float red[4];

  const int tid = (int)threadIdx.x;
  const int tx = tid & 15;
  const int ty = tid >> 4;
  const int row0 = 4 * ty;
  const int col0 = 4 * tx;
  const float* src = adj + (size_t)blockIdx.x * 4096;

  float x[4][4], sc[4][4];
#pragma unroll
  for (int r = 0; r < 4; ++r) {
    v4f v = *(const v4f*)(src + (row0 + r) * 64 + col0);
#pragma unroll
    for (int c = 0; c < 4; ++c) {
      x[r][c] = v[c];
      sc[r][c] = (v[c] > 0.5f) ? v[c] : 0.0f;  // threshold(adj)
    }
  }
  float alpha = 0.0f;

  // Each step packed as 6 bits: sa | sb<<2 | sd<<4.
  const unsigned long long PROG63 =
      16ull | (36ull << 6) | (5ull << 12) | (18ull << 18) | (32ull << 24) |
      (9ull << 30) | (26ull << 36) | (36ull << 42) | (5ull << 48) |
      (18ull << 54);
  const unsigned long long PROG30 =
      32ull | (26ull << 6) | (6ull << 12) | (37ull << 18) | (24ull << 24) |
      (10ull << 30);

  for (int iter = 0; iter < niter; ++iter) {
    float til[4][4];
    if (iter > 0) {
      // B0 = I + (x .* x) / 64
#pragma unroll
      for (int r = 0; r < 4; ++r) {
        v4f v;
#pragma unroll
        for (int c = 0; c < 4; ++c)
          v[c] = x[r][c] * x[r][c] * 0.015625f +
                 ((row0 + r == col0 + c) ? 1.0f : 0.0f);
        *(v4f*)(BUF + (row0 + r) * LDS_S + col0) = v;
      }
      __syncthreads();
      unsigned long long p = PROG63;
      for (int s = 0; s < 10; ++s, p >>= 6) {
        int v = (int)(p & 63ull);
        mm64(BUF + (v & 3) * MSZ, BUF + ((v >> 2) & 3) * MSZ,
             BUF + ((v >> 4) & 3) * MSZ, row0, col0);
      }
      // grad = -scores + 2*alpha*x .* poly^T / 64 ; poly in B1, read transposed.
#pragma unroll
      for (int r = 0; r < 4; ++r)
#pragma unroll
        for (int c = 0; c < 4; ++c) {
          float pt = BUF[MSZ + (col0 + c) * LDS_S + (row0 + r)];
          float g = fmaf(2.0f * alpha * x[r][c] * 0.015625f, pt, -sc[r][c]);
          til[r][c] = fmaf(-0.01f, g, x[r][c]);
        }
    } else {
      // alpha == 0 exactly: grad = -scores, skip the m^63 chain entirely.
#pragma unroll
      for (int r = 0; r < 4; ++r)
#pragma unroll
        for (int c = 0; c < 4; ++c)
          til[r][c] = fmaf(0.01f, sc[r][c], x[r][c]);
    }
    // prox: new_x = relu(|til| - 2e-5); x = min(new_x, 1)
#pragma unroll
    for (int r = 0; r < 4; ++r)
#pragma unroll
      for (int c = 0; c < 4; ++c) {
        float ax = fabsf(til[r][c]) - 2e-5f;
        float nx = ax > 0.0f ? ax : 0.0f;
        x[r][c] = nx > 1.0f ? 1.0f : nx;
      }
    // B0 = I + (x' .* x') / 64   (updated x)
#pragma unroll
    for (int r = 0; r < 4; ++r) {
      v4f v;
#pragma unroll
      for (int c = 0; c < 4; ++c)
        v[c] = x[r][c] * x[r][c] * 0.015625f +
               ((row0 + r == col0 + c) ? 1.0f : 0.0f);
      *(v4f*)(BUF + (row0 + r) * LDS_S + col0) = v;
    }
    __syncthreads();
    unsigned long long q = PROG30;
    for (int s = 0; s < 6; ++s, q >>= 6) {
      int v = (int)(q & 63ull);
      mm64(BUF + (v & 3) * MSZ, BUF + ((v >> 2) & 3) * MSZ,
           BUF + ((v >> 4) & 3) * MSZ, row0, col0);
    }
    // trace(m^30) = sum_{i,k} B1[i,k] * B0[k,i]
    float part = 0.0f;
#pragma unroll
    for (int r = 0; r < 4; ++r)
#pragma unroll
      for (int c = 0; c < 4; ++c)
        part = fmaf(BUF[MSZ + (row0 + r) * LDS_S + col0 + c],
                    BUF[(col0 + c) * LDS_S + (row0 + r)], part);
#pragma unroll
    for (int off = 32; off > 0; off >>= 1) part += __shfl_down(part, off);
    if ((tid & 63) == 0) red[tid >> 6] = part;
    __syncthreads();
    float tr = red[0] + red[1] + red[2] + red[3];
    alpha = fmaf(0.01f, tr * 0.015625f - 1.0f, alpha);
    // No extra barrier needed: every thread's B0/B1 trace reads precede the
    // reduction barrier, and the next write to B0 is after it.
  }

  float* dst = out + (size_t)blockIdx.x * 4096;
#pragma unroll
  for (int r = 0; r < 4; ++r) {
    v4f v;
#pragma unroll
    for (int c = 0; c < 4; ++c) v[c] = (x[r][c] > 0.5f) ? x[r][c] : 0.0f;
    *(v4f*)(dst + (row0 + r) * 64 + col0) = v;
  }
}

extern "C" void kernel_launch(void* const* d_in, const int* in_sizes, int n_in,
                              void* d_out, int out_size, void* d_ws,
                              size_t ws_size, hipStream_t stream) {
  const float* adj = (const float*)d_in[0];
  float* out = (float*)d_out;
  const int nbatch = in_sizes[0] / 4096;  // 512
  dag_iter_kernel<<<nbatch, 256, 0, stream>>>(adj, out, 50);
}

// Round 2
// 538.219 us; speedup vs baseline: 5.0751x; 5.0751x over previous
//
#include <hip/hip_runtime.h>
#include <stdint.h>

// Storage: every 64x64 matrix lives in LDS as one dword per element:
//   bits[15:0]  = bf16 hi part (trunc of fp32)
//   bits[31:16] = bf16 lo part (trunc of residual) -> combined ~2^-16 rel err
// Row-major with stride 66 dwords: 66%32=2 -> all wave-parallel accesses are
// <=2-way bank aliased (free on CDNA4 per m136), rows stay 8B aligned.
#define S 66
#define MSZ (64 * S)

typedef float f32x4 __attribute__((ext_vector_type(4)));
typedef short short8 __attribute__((ext_vector_type(8)));
typedef unsigned int u32;

union Frag { int4 i; short8 s; };

__device__ __forceinline__ u32 prm(u32 a, u32 b, u32 sel) {
  return __builtin_amdgcn_perm(a, b, sel);
}
// reconstruct fp32 from packed hi/lo bf16 dword
__device__ __forceinline__ float rec(u32 w) {
  return __uint_as_float(w << 16) + __uint_as_float(w & 0xffff0000u);
}
// split fp32 into packed hi/lo bf16 dword (truncation; residual is exact)
__device__ __forceinline__ u32 pack_hl(float v) {
  u32 vb = __float_as_uint(v);
  float hf = __uint_as_float(vb & 0xffff0000u);
  u32 lb = __float_as_uint(v - hf);
  return (vb >> 16) | (lb & 0xffff0000u);
}

// SEL constants: build {hi(e0),hi(e1)} and {lo(e0),lo(e1)} dwords from two
// packed element dwords (e0 = src1/b, e1 = src0/a of v_perm).
#define SEL_HI 0x05040100u
#define SEL_LO 0x07060302u

// C = A @ B, 64x64, split-bf16 MFMA engine. 4 waves: wave w owns the 32x32
// quadrant (rh=32*(w>>1), ch=32*(w&1)) as a 2x2 grid of 16x16 MFMA tiles.
// Dest must not alias either source. Ends with __syncthreads().
__device__ __forceinline__ void mm64(const u32* __restrict__ A,
                                     const u32* __restrict__ B,
                                     u32* __restrict__ C, int tid) {
  const int lane = tid & 63;
  const int wv = tid >> 6;
  const int rh = (wv >> 1) << 5;
  const int ch = (wv & 1) << 5;
  const int l15 = lane & 15;
  const int quad8 = ((lane >> 4) & 3) << 3;  // 0,8,16,24

  f32x4 acc[2][2];
#pragma unroll
  for (int i = 0; i < 2; ++i)
#pragma unroll
    for (int j = 0; j < 2; ++j)
#pragma unroll
      for (int e = 0; e < 4; ++e) acc[i][j][e] = 0.0f;

#pragma unroll
  for (int q = 0; q < 2; ++q) {
    const int kb = q * 32 + quad8;  // this lane's first k of the chunk
    Frag ah[2], al[2], bh[2], bl[2];
#pragma unroll
    for (int t = 0; t < 2; ++t) {
      // A-operand: A[m = rh+16t+l15][k = kb..kb+8) ; contiguous dwords, 8B aligned
      const uint2* pa = (const uint2*)(A + (rh + t * 16 + l15) * S + kb);
      uint2 a0 = pa[0], a1 = pa[1], a2 = pa[2], a3 = pa[3];
      ah[t].i = make_int4(prm(a0.y, a0.x, SEL_HI), prm(a1.y, a1.x, SEL_HI),
                          prm(a2.y, a2.x, SEL_HI), prm(a3.y, a3.x, SEL_HI));
      al[t].i = make_int4(prm(a0.y, a0.x, SEL_LO), prm(a1.y, a1.x, SEL_LO),
                          prm(a2.y, a2.x, SEL_LO), prm(a3.y, a3.x, SEL_LO));
      // B-operand: B[k = kb..kb+8)][n = ch+16t+l15] ; column walk, stride S
      const u32* pb = B + kb * S + ch + t * 16 + l15;
      u32 b0 = pb[0], b1 = pb[S], b2 = pb[2 * S], b3 = pb[3 * S];
      u32 b4 = pb[4 * S], b5 = pb[5 * S], b6 = pb[6 * S], b7 = pb[7 * S];
      bh[t].i = make_int4(prm(b1, b0, SEL_HI), prm(b3, b2, SEL_HI),
                          prm(b5, b4, SEL_HI), prm(b7, b6, SEL_HI));
      bl[t].i = make_int4(prm(b1, b0, SEL_LO), prm(b3, b2, SEL_LO),
                          prm(b5, b4, SEL_LO), prm(b7, b6, SEL_LO));
    }
#pragma unroll
    for (int ti = 0; ti < 2; ++ti)
#pragma unroll
      for (int tj = 0; tj < 2; ++tj) {
        acc[ti][tj] = __builtin_amdgcn_mfma_f32_16x16x32_bf16(
            ah[ti].s, bh[tj].s, acc[ti][tj], 0, 0, 0);
        acc[ti][tj] = __builtin_amdgcn_mfma_f32_16x16x32_bf16(
            ah[ti].s, bl[tj].s, acc[ti][tj], 0, 0, 0);
        acc[ti][tj] = __builtin_amdgcn_mfma_f32_16x16x32_bf16(
            al[ti].s, bh[tj].s, acc[ti][tj], 0, 0, 0);
      }
  }
  // C/D layout: col = l15, row = (lane>>4)*4 + reg
  const int r4 = ((lane >> 4) & 3) << 2;
#pragma unroll
  for (int ti = 0; ti < 2; ++ti)
#pragma unroll
    for (int tj = 0; tj < 2; ++tj) {
      u32* pc = C + (rh + ti * 16 + r4) * S + ch + tj * 16 + l15;
#pragma unroll
      for (int r = 0; r < 4; ++r) pc[r * S] = pack_hl(acc[ti][tj][r]);
    }
  __syncthreads();
}

// One block (256 thr) per batch element. Per-thread 4x4 element ownership
// (16x16 thread grid) for all elementwise work; x, scores, alpha in registers.
//
// Addition chain per iter (8 matmuls, 3 buffers):
//   carry-in from prev iter's trace chain: B0 = m15, B2 = m3  (same matrix!)
//   m30=B0*B0->B1; m60=B1*B1->B0; m63=B0*B2->B1       (3 mm, iters>=1)
//   grad/prox -> new x; stage m(new x)->B0
//   m2->B1; m3=B1*B0->B2; m6=B2*B2->B0; m12=B0*B0->B1; m15=B1*B2->B0  (5 mm)
//   tr(m^30) = sum_ik m15[i,k]*m15[k,i]; alpha += 0.01*(tr/64 - 1)
// Last iteration skips the trace chain (its results are dead).
__global__ __launch_bounds__(256, 2) void dag_iter_kernel(
    const float* __restrict__ adj, float* __restrict__ out, int niter) {
  __shared__ __align__(16) u32 BUF[3 * MSZ];
  __shared__ float red[4];
  u32* B0 = BUF;
  u32* B1 = BUF + MSZ;
  u32* B2 = BUF + 2 * MSZ;

  const int tid = (int)threadIdx.x;
  const int tx = tid & 15;
  const int ty = tid >> 4;
  const int row0 = ty * 4;
  const int col0 = tx * 4;
  const float* src = adj + (size_t)blockIdx.x * 4096;

  float x[4][4], sc[4][4];
#pragma unroll
  for (int r = 0; r < 4; ++r) {
    f32x4 v = *(const f32x4*)(src + (row0 + r) * 64 + col0);
#pragma unroll
    for (int c = 0; c < 4; ++c) {
      x[r][c] = v[c];
      sc[r][c] = (v[c] > 0.5f) ? v[c] : 0.0f;
    }
  }
  float alpha = 0.0f;

  for (int iter = 0; iter < niter; ++iter) {
    float til[4][4];
    if (iter == 0) {
      // alpha == 0 exactly: grad = -scores
#pragma unroll
      for (int r = 0; r < 4; ++r)
#pragma unroll
        for (int c = 0; c < 4; ++c)
          til[r][c] = fmaf(0.01f, sc[r][c], x[r][c]);
    } else {
      mm64(B0, B0, B1, tid);  // m30 = m15^2
      mm64(B1, B1, B0, tid);  // m60 = m30^2
      mm64(B0, B2, B1, tid);  // m63 = m60*m3
      const float a2 = alpha * 0.03125f;  // 2*alpha/64
#pragma unroll
      for (int r = 0; r < 4; ++r)
#pragma unroll
        for (int c = 0; c < 4; ++c) {
          float pt = rec(B1[(col0 + c) * S + row0 + r]);  // m63^T
          float g = fmaf(a2 * x[r][c], pt, -sc[r][c]);
          til[r][c] = fmaf(-0.01f, g, x[r][c]);
        }
    }
    // prox: relu(|til| - 2e-5) then clamp to <= 1
#pragma unroll
    for (int r = 0; r < 4; ++r)
#pragma unroll
      for (int c = 0; c < 4; ++c) {
        float ax = fabsf(til[r][c]) - 2e-5f;
        float nx = ax > 0.0f ? ax : 0.0f;
        x[r][c] = nx > 1.0f ? 1.0f : nx;
      }
    if (iter + 1 < niter) {
      // stage B0 = I + x.*x/64 (updated x)
#pragma unroll
      for (int r = 0; r < 4; ++r)
#pragma unroll
        for (int c = 0; c < 4; ++c) {
          float m = fmaf(x[r][c] * x[r][c], 0.015625f,
                         (row0 + r == col0 + c) ? 1.0f : 0.0f);
          B0[(row0 + r) * S + col0 + c] = pack_hl(m);
        }
      __syncthreads();
      mm64(B0, B0, B1, tid);  // m2
      mm64(B1, B0, B2, tid);  // m3 = m2*m
      mm64(B2, B2, B0, tid);  // m6 = m3^2
      mm64(B0, B0, B1, tid);  // m12 = m6^2
      mm64(B1, B2, B0, tid);  // m15 = m12*m3
      // trace(m^30) = sum_{i,k} m15[i,k]*m15[k,i]
      float part = 0.0f;
#pragma unroll
      for (int r = 0; r < 4; ++r)
#pragma unroll
        for (int c = 0; c < 4; ++c)
          part = fmaf(rec(B0[(row0 + r) * S + col0 + c]),
                      rec(B0[(col0 + c) * S + row0 + r]), part);
#pragma unroll
      for (int off = 32; off > 0; off >>= 1) part += __shfl_down(part, off);
      if ((tid & 63) == 0) red[tid >> 6] = part;
      __syncthreads();
      float tr = red[0] + red[1] + red[2] + red[3];
      alpha = fmaf(0.01f, tr * 0.015625f - 1.0f, alpha);
    }
  }

  float* dst = out + (size_t)blockIdx.x * 4096;
#pragma unroll
  for (int r = 0; r < 4; ++r) {
    f32x4 v;
#pragma unroll
    for (int c = 0; c < 4; ++c) v[c] = (x[r][c] > 0.5f) ? x[r][c] : 0.0f;
    *(f32x4*)(dst + (row0 + r) * 64 + col0) = v;
  }
}

extern "C" void kernel_launch(void* const* d_in, const int* in_sizes, int n_in,
                              void* d_out, int out_size, void* d_ws,
                              size_t ws_size, hipStream_t stream) {
  const float* adj = (const float*)d_in[0];
  float* out = (float*)d_out;
  const int nbatch = in_sizes[0] / 4096;  // 512
  dag_iter_kernel<<<nbatch, 256, 0, stream>>>(adj, out, 50);
}

// Round 3
// 356.093 us; speedup vs baseline: 7.6707x; 1.5115x over previous
//
#include <hip/hip_runtime.h>
#include <stdint.h>

// Every 64x64 matrix is stored in LDS as TWO bf16 planes:
//   R-plane: row-major,  R[m][k]  -> MFMA A-fragment = one ds_read_b128
//   T-plane: transposed, T[n][m]=M[m][n] -> MFMA B-fragment = one ds_read_b128
// Row stride 72 shorts (144 B): rows stay 16B-aligned for b128; 144/4=36 ≡ 4
// (mod 32) gives uniform bank coverage for the 16-lane row walks.
#define SH 72
#define PLANE (64 * SH)

typedef unsigned int u32;
typedef unsigned short u16;
typedef float f32x4 __attribute__((ext_vector_type(4)));
typedef short short8 __attribute__((ext_vector_type(8)));

// v_perm: __builtin_amdgcn_perm(A, B, sel): sel bytes 0-3 pick from B, 4-7
// from A (semantics verified by round-2 pass).
__device__ __forceinline__ u32 prm(u32 a, u32 b, u32 s) {
  return __builtin_amdgcn_perm(a, b, s);
}
// pack {bf16(f0) low16, bf16(f1) high16} (truncation)
__device__ __forceinline__ u32 pk(float f0, float f1) {
  return prm(__float_as_uint(f1), __float_as_uint(f0), 0x07060302u);
}
__device__ __forceinline__ float rlo(u32 w) { return __uint_as_float(w << 16); }
__device__ __forceinline__ float rhi(u32 w) {
  return __uint_as_float(w & 0xffff0000u);
}

// C = A @ B (64x64 bf16). Wave wv owns quadrant (rh,ch) as 2x2 16x16 tiles.
// Reads A.R and B.T; writes C.R and C.T. Dest != sources. Trailing barrier.
__device__ __forceinline__ void mm64(const u16* __restrict__ AR,
                                     const u16* __restrict__ BT,
                                     u16* __restrict__ CR,
                                     u16* __restrict__ CT, int tid) {
  const int lane = tid & 63;
  const int wv = tid >> 6;
  const int rh = (wv >> 1) << 5;
  const int ch = (wv & 1) << 5;
  const int l15 = lane & 15;
  const int grp = (lane >> 4) & 3;
  const int q8 = grp << 3;  // k offset within 32-chunk
  const int r4 = grp << 2;  // C/D row group

  f32x4 acc[2][2];
#pragma unroll
  for (int i = 0; i < 2; ++i)
#pragma unroll
    for (int j = 0; j < 2; ++j)
#pragma unroll
      for (int e = 0; e < 4; ++e) acc[i][j][e] = 0.0f;

#pragma unroll
  for (int q = 0; q < 2; ++q) {
    const int kb = q * 32 + q8;
    short8 a[2], b[2];
#pragma unroll
    for (int t = 0; t < 2; ++t) {
      a[t] = *(const short8*)(AR + (rh + t * 16 + l15) * SH + kb);
      b[t] = *(const short8*)(BT + (ch + t * 16 + l15) * SH + kb);
    }
#pragma unroll
    for (int ti = 0; ti < 2; ++ti)
#pragma unroll
      for (int tj = 0; tj < 2; ++tj)
        acc[ti][tj] = __builtin_amdgcn_mfma_f32_16x16x32_bf16(
            a[ti], b[tj], acc[ti][tj], 0, 0, 0);
  }
  // C/D layout: col = l15, row = r4 + reg (verified).
#pragma unroll
  for (int ti = 0; ti < 2; ++ti)
#pragma unroll
    for (int tj = 0; tj < 2; ++tj) {
      const int row0 = rh + ti * 16 + r4;
      const int col = ch + tj * 16 + l15;
      f32x4 v = acc[ti][tj];
      // R-plane: 4 scattered b16 stores (rows differ)
#pragma unroll
      for (int r = 0; r < 4; ++r)
        CR[(row0 + r) * SH + col] = (u16)(__float_as_uint(v[r]) >> 16);
      // T-plane: T[col][row0..row0+3] contiguous -> one 8B store
      *(uint2*)(CT + col * SH + row0) =
          make_uint2(pk(v[0], v[1]), pk(v[2], v[3]));
    }
  __syncthreads();
}

// One block (256 thr) per batch element; x, scores, alpha in registers.
// Addition chain per iter (8 matmuls, 3 dual-plane buffers):
//   carry-in: B0 = m15, B2 = m3 (of the SAME matrix the grad chain needs)
//   m30=B0*B0->B1; m60=B1*B1->B0; m63=B0*B2->B1        (iters>=1)
//   grad/prox -> new x; stage m(new x)->B0 (both planes)
//   m2->B1; m3=B1*B0->B2; m6=B2*B2->B0; m12=B0*B0->B1; m15=B1*B2->B0
//   tr(m^30)=sum m15[i,k]*m15[k,i] = sum R15.*T15 elementwise
// Last iteration skips the staging/trace chain (dead).
__global__ __launch_bounds__(256, 2) void dag_iter_kernel(
    const float* __restrict__ adj, float* __restrict__ out, int niter) {
  __shared__ __align__(16) u16 BUF[6 * PLANE];
  __shared__ float red[4];
  u16* R0 = BUF;
  u16* T0 = BUF + PLANE;
  u16* R1 = BUF + 2 * PLANE;
  u16* T1 = BUF + 3 * PLANE;
  u16* R2 = BUF + 4 * PLANE;
  u16* T2 = BUF + 5 * PLANE;

  const int tid = (int)threadIdx.x;
  const int tx = tid & 15;
  const int ty = tid >> 4;
  const int row0 = ty * 4;
  const int col0 = tx * 4;
  const float* src = adj + (size_t)blockIdx.x * 4096;

  float x[4][4], sc[4][4];
#pragma unroll
  for (int r = 0; r < 4; ++r) {
    f32x4 v = *(const f32x4*)(src + (row0 + r) * 64 + col0);
#pragma unroll
    for (int c = 0; c < 4; ++c) {
      x[r][c] = v[c];
      sc[r][c] = (v[c] > 0.5f) ? v[c] : 0.0f;
    }
  }
  float alpha = 0.0f;

  for (int iter = 0; iter < niter; ++iter) {
    float til[4][4];
    if (iter == 0) {
      // alpha == 0 exactly: grad = -scores
#pragma unroll
      for (int r = 0; r < 4; ++r)
#pragma unroll
        for (int c = 0; c < 4; ++c)
          til[r][c] = fmaf(0.01f, sc[r][c], x[r][c]);
    } else {
      mm64(R0, T0, R1, T1, tid);  // m30 = m15^2
      mm64(R1, T1, R0, T0, tid);  // m60 = m30^2
      mm64(R0, T2, R1, T1, tid);  // m63 = m60*m3
      const float a2 = alpha * 0.03125f;  // 2*alpha/64
#pragma unroll
      for (int r = 0; r < 4; ++r) {
        // pt(r,c) = m63[c][r] = T1[r][c..]: contiguous 4 shorts
        uint2 w = *(const uint2*)(T1 + (row0 + r) * SH + col0);
        float pt[4] = {rlo(w.x), rhi(w.x), rlo(w.y), rhi(w.y)};
#pragma unroll
        for (int c = 0; c < 4; ++c) {
          float g = fmaf(a2 * x[r][c], pt[c], -sc[r][c]);
          til[r][c] = fmaf(-0.01f, g, x[r][c]);
        }
      }
    }
    // prox: relu(|til| - 2e-5) then clamp to <= 1
#pragma unroll
    for (int r = 0; r < 4; ++r)
#pragma unroll
      for (int c = 0; c < 4; ++c) {
        float ax = fabsf(til[r][c]) - 2e-5f;
        float nx = ax > 0.0f ? ax : 0.0f;
        x[r][c] = nx > 1.0f ? 1.0f : nx;
      }
    if (iter + 1 < niter) {
      // stage m = I + x.*x/64 into B0 (both planes)
      float m[4][4];
#pragma unroll
      for (int r = 0; r < 4; ++r)
#pragma unroll
        for (int c = 0; c < 4; ++c)
          m[r][c] = fmaf(x[r][c] * x[r][c], 0.015625f,
                         (row0 + r == col0 + c) ? 1.0f : 0.0f);
#pragma unroll
      for (int r = 0; r < 4; ++r)
        *(uint2*)(R0 + (row0 + r) * SH + col0) =
            make_uint2(pk(m[r][0], m[r][1]), pk(m[r][2], m[r][3]));
#pragma unroll
      for (int c = 0; c < 4; ++c)
        *(uint2*)(T0 + (col0 + c) * SH + row0) =
            make_uint2(pk(m[0][c], m[1][c]), pk(m[2][c], m[3][c]));
      __syncthreads();
      mm64(R0, T0, R1, T1, tid);  // m2
      mm64(R1, T0, R2, T2, tid);  // m3 = m2*m
      mm64(R2, T2, R0, T0, tid);  // m6 = m3^2
      mm64(R0, T0, R1, T1, tid);  // m12 = m6^2
      mm64(R1, T2, R0, T0, tid);  // m15 = m12*m3
      // trace(m^30) = sum_{r,c} R15[r][c] * T15[r][c] (elementwise!)
      float part = 0.0f;
#pragma unroll
      for (int r = 0; r < 4; ++r) {
        uint2 a = *(const uint2*)(R0 + (row0 + r) * SH + col0);
        uint2 b = *(const uint2*)(T0 + (row0 + r) * SH + col0);
        part = fmaf(rlo(a.x), rlo(b.x), part);
        part = fmaf(rhi(a.x), rhi(b.x), part);
        part = fmaf(rlo(a.y), rlo(b.y), part);
        part = fmaf(rhi(a.y), rhi(b.y), part);
      }
#pragma unroll
      for (int off = 32; off > 0; off >>= 1) part += __shfl_down(part, off);
      if ((tid & 63) == 0) red[tid >> 6] = part;
      __syncthreads();
      float tr = red[0] + red[1] + red[2] + red[3];
      alpha = fmaf(0.01f, tr * 0.015625f - 1.0f, alpha);
    }
  }

  float* dst = out + (size_t)blockIdx.x * 4096;
#pragma unroll
  for (int r = 0; r < 4; ++r) {
    f32x4 v;
#pragma unroll
    for (int c = 0; c < 4; ++c) v[c] = (x[r][c] > 0.5f) ? x[r][c] : 0.0f;
    *(f32x4*)(dst + (row0 + r) * 64 + col0) = v;
  }
}

extern "C" void kernel_launch(void* const* d_in, const int* in_sizes, int n_in,
                              void* d_out, int out_size, void* d_ws,
                              size_t ws_size, hipStream_t stream) {
  const float* adj = (const float*)d_in[0];
  float* out = (float*)d_out;
  const int nbatch = in_sizes[0] / 4096;  // 512
  dag_iter_kernel<<<nbatch, 256, 0, stream>>>(adj, out, 50);
}

// Round 4
// 305.974 us; speedup vs baseline: 8.9272x; 1.1638x over previous
//
#include <hip/hip_runtime.h>
#include <stdint.h>

// Each 64x64 matrix: TWO bf16 planes in LDS, unpadded stride 64, XOR-swizzled:
//   element [r][c] lives at short-index  r*64 + (((c>>3) ^ (r&7))<<3) + (c&7)
//   R-plane: C row-major  -> MFMA A-fragment = one ds_read_b128
//   T-plane: C^T row-major-> MFMA B-fragment = one ds_read_b128
// The swizzle makes both the 16-lane row-parallel b128 reads and the b64 tile
// stores hit all 32 banks uniformly (8 resp. 4 touches/bank = issue floor).
#define PLANE 4096  // 64*64 shorts = 8 KB

typedef unsigned int u32;
typedef unsigned short u16;
typedef float f32x4 __attribute__((ext_vector_type(4)));
typedef short short8 __attribute__((ext_vector_type(8)));

__device__ __forceinline__ u32 prm(u32 a, u32 b, u32 s) {
  return __builtin_amdgcn_perm(a, b, s);
}
// pack {bf16(f0) low16, bf16(f1) high16} (truncation)
__device__ __forceinline__ u32 pk(float f0, float f1) {
  return prm(__float_as_uint(f1), __float_as_uint(f0), 0x07060302u);
}
__device__ __forceinline__ float rlo(u32 w) { return __uint_as_float(w << 16); }
__device__ __forceinline__ float rhi(u32 w) {
  return __uint_as_float(w & 0xffff0000u);
}
// swizzled short-index of element [r][c] within a plane
__device__ __forceinline__ int sidx(int r, int c) {
  return r * 64 + ((((c >> 3) ^ r) & 7) << 3) + (c & 7);
}

// Precomputed per-thread LDS short-offsets for the matmul fragments/stores.
struct Off {
  int a[2][2];   // A-frag read, [t][q]
  int b[2][2];   // B-frag read, [t][q]
  int st[2][2];  // T-plane store for acc[ti][tj]
  int sr[2][2];  // R-plane store for acc2[tj][ti]
};

// C = A @ B (64x64 bf16). Wave wv owns quadrant (rh,ch) as 2x2 16x16 tiles.
// Computes each product twice (operands mirrored) so BOTH planes of C are
// written with contiguous b64 stores:
//   acc [ti][tj] = A.R x B.T  -> D col-major   -> C^T contiguous -> T-plane
//   acc2[tj][ti] = B.T x A.R  (= C^T as a product) -> C contiguous -> R-plane
// Dest != sources. Trailing barrier.
__device__ __forceinline__ void mm64(const u16* __restrict__ AR,
                                     const u16* __restrict__ BT,
                                     u16* __restrict__ CR,
                                     u16* __restrict__ CT, const Off& o) {
  short8 af[2][2], bf[2][2];
#pragma unroll
  for (int t = 0; t < 2; ++t)
#pragma unroll
    for (int q = 0; q < 2; ++q) {
      af[t][q] = *(const short8*)(AR + o.a[t][q]);
      bf[t][q] = *(const short8*)(BT + o.b[t][q]);
    }
  f32x4 acc[2][2], acc2[2][2];
#pragma unroll
  for (int i = 0; i < 2; ++i)
#pragma unroll
    for (int j = 0; j < 2; ++j)
#pragma unroll
      for (int e = 0; e < 4; ++e) {
        acc[i][j][e] = 0.0f;
        acc2[i][j][e] = 0.0f;
      }
#pragma unroll
  for (int q = 0; q < 2; ++q)
#pragma unroll
    for (int ti = 0; ti < 2; ++ti)
#pragma unroll
      for (int tj = 0; tj < 2; ++tj) {
        acc[ti][tj] = __builtin_amdgcn_mfma_f32_16x16x32_bf16(
            af[ti][q], bf[tj][q], acc[ti][tj], 0, 0, 0);
        acc2[tj][ti] = __builtin_amdgcn_mfma_f32_16x16x32_bf16(
            bf[tj][q], af[ti][q], acc2[tj][ti], 0, 0, 0);
      }
#pragma unroll
  for (int ti = 0; ti < 2; ++ti)
#pragma unroll
    for (int tj = 0; tj < 2; ++tj) {
      f32x4 v = acc[ti][tj];
      *(uint2*)(CT + o.st[ti][tj]) =
          make_uint2(pk(v[0], v[1]), pk(v[2], v[3]));
      f32x4 w = acc2[tj][ti];
      *(uint2*)(CR + o.sr[ti][tj]) =
          make_uint2(pk(w[0], w[1]), pk(w[2], w[3]));
    }
  __syncthreads();
}

// One block (256 thr) per batch element; x, scores, alpha in registers.
// Addition chain per iter (8 matmuls, 3 dual-plane buffers):
//   carry-in: B0 = m15, B2 = m3 (of the SAME matrix the grad chain needs)
//   m30=B0*B0->B1; m60=B1*B1->B0; m63=B0*B2->B1        (iters>=1)
//   grad/prox -> new x; stage m(new x)->B0 (both planes)
//   m2->B1; m3=B1*B0->B2; m6=B2*B2->B0; m12=B0*B0->B1; m15=B1*B2->B0
//   tr(m^30)=sum m15[i,k]*m15[k,i] = sum R15.*T15 elementwise
// Last iteration skips the staging/trace chain (dead).
__global__ __launch_bounds__(256, 2) void dag_iter_kernel(
    const float* __restrict__ adj, float* __restrict__ out, int niter) {
  __shared__ __align__(16) u16 BUF[6 * PLANE];
  __shared__ float red[4];
  u16* R0 = BUF;
  u16* T0 = BUF + PLANE;
  u16* R1 = BUF + 2 * PLANE;
  u16* T1 = BUF + 3 * PLANE;
  u16* R2 = BUF + 4 * PLANE;
  u16* T2 = BUF + 5 * PLANE;

  const int tid = (int)threadIdx.x;
  const int tx = tid & 15;
  const int ty = tid >> 4;
  const int row0 = ty * 4;
  const int col0 = tx * 4;
  const float* src = adj + (size_t)blockIdx.x * 4096;

  // fragment/store offsets for this thread
  Off o;
  {
    const int lane = tid & 63;
    const int wv = tid >> 6;
    const int rh = (wv >> 1) << 5;
    const int ch = (wv & 1) << 5;
    const int l15 = lane & 15;
    const int grp = (lane >> 4) & 3;
    const int l7 = l15 & 7;
#pragma unroll
    for (int t = 0; t < 2; ++t)
#pragma unroll
      for (int q = 0; q < 2; ++q) {
        const int kblk = ((q << 2) + grp) ^ l7;
        o.a[t][q] = (rh + 16 * t + l15) * 64 + (kblk << 3);
        o.b[t][q] = (ch + 16 * t + l15) * 64 + (kblk << 3);
      }
#pragma unroll
    for (int ti = 0; ti < 2; ++ti)
#pragma unroll
      for (int tj = 0; tj < 2; ++tj) {
        // T-plane: row = ch+16tj+l15, col-run p0 = rh+16ti+4*grp
        o.st[ti][tj] = (ch + 16 * tj + l15) * 64 +
                       (((((rh + 16 * ti) >> 3) + (grp >> 1)) ^ l7) << 3) +
                       ((grp & 1) << 2);
        // R-plane: row = rh+16ti+l15, col-run p0 = ch+16tj+4*grp
        o.sr[ti][tj] = (rh + 16 * ti + l15) * 64 +
                       (((((ch + 16 * tj) >> 3) + (grp >> 1)) ^ l7) << 3) +
                       ((grp & 1) << 2);
      }
  }

  float x[4][4], sc[4][4];
#pragma unroll
  for (int r = 0; r < 4; ++r) {
    f32x4 v = *(const f32x4*)(src + (row0 + r) * 64 + col0);
#pragma unroll
    for (int c = 0; c < 4; ++c) {
      x[r][c] = v[c];
      sc[r][c] = (v[c] > 0.5f) ? v[c] : 0.0f;
    }
  }
  float alpha = 0.0f;

  for (int iter = 0; iter < niter; ++iter) {
    float til[4][4];
    if (iter == 0) {
      // alpha == 0 exactly: grad = -scores
#pragma unroll
      for (int r = 0; r < 4; ++r)
#pragma unroll
        for (int c = 0; c < 4; ++c)
          til[r][c] = fmaf(0.01f, sc[r][c], x[r][c]);
    } else {
      mm64(R0, T0, R1, T1, o);  // m30 = m15^2
      mm64(R1, T1, R0, T0, o);  // m60 = m30^2
      mm64(R0, T2, R1, T1, o);  // m63 = m60*m3
      const float a2 = alpha * 0.03125f;  // 2*alpha/64
#pragma unroll
      for (int r = 0; r < 4; ++r) {
        // pt(r,c) = m63[c][r] = T1[row0+r][col0+c]: contiguous 4 shorts
        uint2 w = *(const uint2*)(T1 + sidx(row0 + r, col0));
        float pt[4] = {rlo(w.x), rhi(w.x), rlo(w.y), rhi(w.y)};
#pragma unroll
        for (int c = 0; c < 4; ++c) {
          float g = fmaf(a2 * x[r][c], pt[c], -sc[r][c]);
          til[r][c] = fmaf(-0.01f, g, x[r][c]);
        }
      }
    }
    // prox: relu(|til| - 2e-5) then clamp to <= 1
#pragma unroll
    for (int r = 0; r < 4; ++r)
#pragma unroll
      for (int c = 0; c < 4; ++c) {
        float ax = fabsf(til[r][c]) - 2e-5f;
        float nx = ax > 0.0f ? ax : 0.0f;
        x[r][c] = nx > 1.0f ? 1.0f : nx;
      }
    if (iter + 1 < niter) {
      // stage m = I + x.*x/64 into B0 (both planes)
      float m[4][4];
#pragma unroll
      for (int r = 0; r < 4; ++r)
#pragma unroll
        for (int c = 0; c < 4; ++c)
          m[r][c] = fmaf(x[r][c] * x[r][c], 0.015625f,
                         (row0 + r == col0 + c) ? 1.0f : 0.0f);
#pragma unroll
      for (int r = 0; r < 4; ++r)
        *(uint2*)(R0 + sidx(row0 + r, col0)) =
            make_uint2(pk(m[r][0], m[r][1]), pk(m[r][2], m[r][3]));
#pragma unroll
      for (int c = 0; c < 4; ++c)
        *(uint2*)(T0 + sidx(col0 + c, row0)) =
            make_uint2(pk(m[0][c], m[1][c]), pk(m[2][c], m[3][c]));
      __syncthreads();
      mm64(R0, T0, R1, T1, o);  // m2
      mm64(R1, T0, R2, T2, o);  // m3 = m2*m
      mm64(R2, T2, R0, T0, o);  // m6 = m3^2
      mm64(R0, T0, R1, T1, o);  // m12 = m6^2
      mm64(R1, T2, R0, T0, o);  // m15 = m12*m3
      // trace(m^30) = sum_{r,c} R15[r][c]*T15[r][c] (elementwise; swizzle
      // cancels since both planes share the same physical layout map)
      float part = 0.0f;
#pragma unroll
      for (int r = 0; r < 4; ++r) {
        uint2 a = *(const uint2*)(R0 + sidx(row0 + r, col0));
        uint2 b = *(const uint2*)(T0 + sidx(row0 + r, col0));
        part = fmaf(rlo(a.x), rlo(b.x), part);
        part = fmaf(rhi(a.x), rhi(b.x), part);
        part = fmaf(rlo(a.y), rlo(b.y), part);
        part = fmaf(rhi(a.y), rhi(b.y), part);
      }
#pragma unroll
      for (int off = 32; off > 0; off >>= 1) part += __shfl_down(part, off);
      if ((tid & 63) == 0) red[tid >> 6] = part;
      __syncthreads();
      float tr = red[0] + red[1] + red[2] + red[3];
      alpha = fmaf(0.01f, tr * 0.015625f - 1.0f, alpha);
    }
  }

  float* dst = out + (size_t)blockIdx.x * 4096;
#pragma unroll
  for (int r = 0; r < 4; ++r) {
    f32x4 v;
#pragma unroll
    for (int c = 0; c < 4; ++c) v[c] = (x[r][c] > 0.5f) ? x[r][c] : 0.0f;
    *(f32x4*)(dst + (row0 + r) * 64 + col0) = v;
  }
}

extern "C" void kernel_launch(void* const* d_in, const int* in_sizes, int n_in,
                              void* d_out, int out_size, void* d_ws,
                              size_t ws_size, hipStream_t stream) {
  const float* adj = (const float*)d_in[0];
  float* out = (float*)d_out;
  const int nbatch = in_sizes[0] / 4096;  // 512
  dag_iter_kernel<<<nbatch, 256, 0, stream>>>(adj, out, 50);
}